// Round 15
// baseline (497.363 us; speedup 1.0000x reference)
//
#include <hip/hip_runtime.h>
#include <hip/hip_bf16.h>

// ---------- helpers ----------

__device__ __forceinline__ unsigned short f2bf(float f) {
    unsigned u = __float_as_uint(f);
    unsigned r = u + 0x7fffu + ((u >> 16) & 1u);
    return (unsigned short)(r >> 16);
}

typedef __bf16 bf16_t;
typedef bf16_t bf16x8 __attribute__((ext_vector_type(8)));
typedef float f32x4 __attribute__((ext_vector_type(4)));

typedef const __attribute__((address_space(1))) unsigned int* gptr_t;
typedef __attribute__((address_space(3))) unsigned int* lptr_t;

__device__ __forceinline__ void gload_lds16(const void* g, void* l) {
    __builtin_amdgcn_global_load_lds((gptr_t)g, (lptr_t)l, 16, 0, 0);
}

// ---------- kernel 1: fused column-max of |x| AND column-max+convert of W ----------
__global__ void maxes_kernel(const float* __restrict__ x, int xrows,
                             const float* __restrict__ W, int wrows,
                             unsigned int* __restrict__ ma, unsigned int* __restrict__ mw,
                             unsigned short* __restrict__ Wb, int cols, int xBlocks) {
    int c = (blockIdx.x * blockDim.x + threadIdx.x) * 4;
    if (c >= cols) return;
    float m0 = 0.f, m1 = 0.f, m2 = 0.f, m3 = 0.f;
    if ((int)blockIdx.y < xBlocks) {
        int r0 = blockIdx.y * 64;
        int r1 = min(r0 + 64, xrows);
        const float* p = x + (size_t)r0 * cols + c;
        for (int r = r0; r < r1; ++r, p += cols) {
            float4 v = *(const float4*)p;
            m0 = fmaxf(m0, fabsf(v.x));
            m1 = fmaxf(m1, fabsf(v.y));
            m2 = fmaxf(m2, fabsf(v.z));
            m3 = fmaxf(m3, fabsf(v.w));
        }
        atomicMax(ma + c + 0, __float_as_uint(m0));
        atomicMax(ma + c + 1, __float_as_uint(m1));
        atomicMax(ma + c + 2, __float_as_uint(m2));
        atomicMax(ma + c + 3, __float_as_uint(m3));
    } else {
        int r0 = ((int)blockIdx.y - xBlocks) * 64;
        int r1 = min(r0 + 64, wrows);
        const float* p = W + (size_t)r0 * cols + c;
        unsigned short* q = Wb + (size_t)r0 * cols + c;
        for (int r = r0; r < r1; ++r, p += cols, q += cols) {
            float4 v = *(const float4*)p;
            ushort4 o;
            o.x = f2bf(v.x); o.y = f2bf(v.y); o.z = f2bf(v.z); o.w = f2bf(v.w);
            *(ushort4*)q = o;
            m0 = fmaxf(m0, fabsf(v.x));
            m1 = fmaxf(m1, fabsf(v.y));
            m2 = fmaxf(m2, fabsf(v.z));
            m3 = fmaxf(m3, fabsf(v.w));
        }
        atomicMax(mw + c + 0, __float_as_uint(m0));
        atomicMax(mw + c + 1, __float_as_uint(m1));
        atomicMax(mw + c + 2, __float_as_uint(m2));
        atomicMax(mw + c + 3, __float_as_uint(m3));
    }
}

// ---------- kernel 2: 2:4 prune of (x/s), s computed inline ----------
__global__ void prune_kernel(const float* __restrict__ x,
                             const unsigned int* __restrict__ ma,
                             const unsigned int* __restrict__ mw,
                             unsigned short* __restrict__ xsp, size_t ngroups, int cols) {
    size_t g = (size_t)blockIdx.x * blockDim.x + threadIdx.x;
    size_t stride = (size_t)gridDim.x * blockDim.x;
    for (; g < ngroups; g += stride) {
        size_t e = g * 4;
        int cb = (int)(e & (size_t)(cols - 1));
        float4 v = *(const float4*)(x + e);
        uint4 mav = *(const uint4*)(ma + cb);
        uint4 mwv = *(const uint4*)(mw + cb);
        float s0 = sqrtf(__uint_as_float(mav.x) / fmaxf(__uint_as_float(mwv.x), 1e-8f));
        float s1 = sqrtf(__uint_as_float(mav.y) / fmaxf(__uint_as_float(mwv.y), 1e-8f));
        float s2 = sqrtf(__uint_as_float(mav.z) / fmaxf(__uint_as_float(mwv.z), 1e-8f));
        float s3 = sqrtf(__uint_as_float(mav.w) / fmaxf(__uint_as_float(mwv.w), 1e-8f));
        float a0 = fabsf(v.x / s0);
        float a1 = fabsf(v.y / s1);
        float a2 = fabsf(v.z / s2);
        float a3 = fabsf(v.w / s3);
        int r0 = 0, r1 = 0, r2 = 0, r3 = 0;
        if (a1 > a0) r0++; else r1++;
        if (a2 > a0) r0++; else r2++;
        if (a3 > a0) r0++; else r3++;
        if (a2 > a1) r1++; else r2++;
        if (a3 > a1) r1++; else r3++;
        if (a3 > a2) r2++; else r3++;
        ushort4 o;
        o.x = (r0 < 2) ? f2bf(v.x) : (unsigned short)0;
        o.y = (r1 < 2) ? f2bf(v.y) : (unsigned short)0;
        o.z = (r2 < 2) ? f2bf(v.z) : (unsigned short)0;
        o.w = (r3 < 2) ? f2bf(v.w) : (unsigned short)0;
        *(ushort4*)(xsp + e) = o;
    }
}

// ---------- kernel 3: 256x256 bf16 B^T GEMM, ONE barrier per K-tile ----------
// Clean-dbuf ledger: iter t reads tile t from buf[t&1] (24 ds_read_b128),
// stages tile t+1 into buf[t^1] (12 gloads). No same-buffer hazard.
// Cross-wave syncs, both satisfied by ONE barrier at iter end:
//   (i) tile-t stages drained before anyone reads cur: every wave's vmcnt(0)
//       precedes barrier(t-1) -> proven at iter entry.
//  (ii) tile-(t-1) reads drained before anyone stages into other: every
//       wave's lgkm(0) precedes its MFMA cluster, hence barrier(t-1).
// vmcnt(0) is cheap: the 12 stages have the ~2500-cy MFMA cluster to land.
// Barrier-section count per K-tile: R2=8 -> R6=4 -> this=2 (1 bar + 1 gate);
// measured trend ~760 cy per removed section.

template <int ISB, int H>
__device__ __forceinline__ void stage_half(const unsigned short* __restrict__ G, int ldk,
                                           long blockBase, int k0, unsigned short* sbuf,
                                           int wid, int l) {
#pragma unroll
    for (int j = 0; j < 2; ++j) {
        int rho0;
        if (ISB) rho0 = ((wid * 8) & 31) + (wid >> 2) * 64 + H * 32 + j * 128;
        else     rho0 = wid * 8 + H * 64 + j * 128;
        int rho = rho0 + (l >> 3);
        int c = l & 7;
        const unsigned short* src =
            G + (size_t)(blockBase + rho) * ldk + k0 + ((c ^ (rho & 7)) << 3);
        gload_lds16(src, (char*)sbuf + rho0 * 128);
    }
}

#define STAGE_A0(k, buf) stage_half<0, 0>(A, K, browBase, (k), (buf), wid, l)
#define STAGE_A1(k, buf) stage_half<0, 1>(A, K, browBase, (k), (buf), wid, l)
#define STAGE_B0(k, buf) stage_half<1, 0>(B, K, bcolBase, (k), (buf), wid, l)
#define STAGE_B1(k, buf) stage_half<1, 1>(B, K, bcolBase, (k), (buf), wid, l)

__global__ __launch_bounds__(512, 2) void gemm_bt256(
        const unsigned short* __restrict__ A,
        const unsigned short* __restrict__ B,
        float* __restrict__ C, int M, int N, int K) {
    __shared__ unsigned short sA[2][256 * 64];
    __shared__ unsigned short sB[2][256 * 64];
    const int tid = threadIdx.x;
    const int l = tid & 63;
    const int wid = tid >> 6;
    const int wr = wid >> 2;
    const int wc = wid & 3;

    // bijective XCD swizzle (nwg % 8 == 0); by-fastest for B-panel L2 locality
    const int nbx = N >> 8, nby = M >> 8;
    const int cpx = (nbx * nby) >> 3;
    const int swz = ((int)blockIdx.x & 7) * cpx + ((int)blockIdx.x >> 3);
    const int by = swz % nby;
    const int bx = swz / nby;
    const long browBase = (long)by << 8;
    const long bcolBase = (long)bx << 8;

    const int NT = K >> 6;

    f32x4 acc[8][4] = {};

    // prologue: tile0 -> buf0; full drain; barrier == steady iter-entry state.
    STAGE_A0(0, sA[0]);
    STAGE_B0(0, sB[0]);
    STAGE_B1(0, sB[0]);
    STAGE_A1(0, sA[0]);
    asm volatile("s_waitcnt vmcnt(0)");
    __builtin_amdgcn_s_barrier();
    __builtin_amdgcn_sched_barrier(0);

    for (int t = 0; t < NT; ++t) {
        const int cur = t & 1;
        const unsigned short* curA = sA[cur];
        const unsigned short* curB = sB[cur];
        unsigned short* oA = (unsigned short*)sA[cur ^ 1];
        unsigned short* oB = (unsigned short*)sB[cur ^ 1];
        // tail clamp: dummy restage of the last tile (regions never read again)
        const int k1 = (t + 1 < NT ? t + 1 : NT - 1) << 6;

        bf16x8 af[8][2], bv[4][2];

        // ---- reads: whole tile t (24 x ds_read_b128) ----
#pragma unroll
        for (int mm = 0; mm < 8; ++mm)
#pragma unroll
            for (int kk = 0; kk < 2; ++kk) {
                int row = wr * 128 + mm * 16 + (l & 15);
                int cl = kk * 4 + (l >> 4);
                af[mm][kk] = *(const bf16x8*)((const char*)curA + row * 128 +
                                              ((cl ^ (row & 7)) << 4));
            }
#pragma unroll
        for (int nn = 0; nn < 4; ++nn)
#pragma unroll
            for (int kk = 0; kk < 2; ++kk) {
                int row = wc * 64 + nn * 16 + (l & 15);
                int cl = kk * 4 + (l >> 4);
                bv[nn][kk] = *(const bf16x8*)((const char*)curB + row * 128 +
                                              ((cl ^ (row & 7)) << 4));
            }

        // ---- stage tile t+1 -> other buffer (12 gloads) ----
        STAGE_A0(k1, oA);
        STAGE_B0(k1, oB);
        STAGE_B1(k1, oB);
        STAGE_A1(k1, oA);

        // ---- compute: 64 MFMA ----
        asm volatile("s_waitcnt lgkmcnt(0)");
        __builtin_amdgcn_sched_barrier(0);
        __builtin_amdgcn_s_setprio(1);
#pragma unroll
        for (int mm = 0; mm < 8; ++mm)
#pragma unroll
            for (int nn = 0; nn < 4; ++nn)
#pragma unroll
                for (int kk = 0; kk < 2; ++kk)
                    acc[mm][nn] = __builtin_amdgcn_mfma_f32_16x16x32_bf16(
                        af[mm][kk], bv[nn][kk], acc[mm][nn], 0, 0, 0);
        __builtin_amdgcn_s_setprio(0);

        // ---- single sync point per K-tile ----
        asm volatile("s_waitcnt vmcnt(0)");
        __builtin_amdgcn_s_barrier();
        __builtin_amdgcn_sched_barrier(0);
    }

    // epilogue: C/D layout col = lane&15, row = (lane>>4)*4 + reg
    const int er = (l >> 4) * 4;
    const int ec = l & 15;
#pragma unroll
    for (int mm = 0; mm < 8; ++mm) {
#pragma unroll
        for (int nn = 0; nn < 4; ++nn) {
            long row = browBase + wr * 128 + mm * 16 + er;
            long col = bcolBase + wc * 64 + nn * 16 + ec;
            float* cp = C + row * N + col;
#pragma unroll
            for (int r = 0; r < 4; ++r)
                cp[(long)r * N] = acc[mm][nn][r];
        }
    }
}

// ---------- launch ----------
extern "C" void kernel_launch(void* const* d_in, const int* in_sizes, int n_in,
                              void* d_out, int out_size, void* d_ws, size_t ws_size,
                              hipStream_t stream) {
    const float* x = (const float*)d_in[0];
    const float* W = (const float*)d_in[1];
    float* out = (float*)d_out;

    const int K = 4096;
    const int Nout = in_sizes[1] / K;             // 4096
    const size_t Mrows = (size_t)in_sizes[0] / K; // 8192

    char* ws = (char*)d_ws;
    unsigned short* Xsp = (unsigned short*)ws;
    unsigned short* Wb = (unsigned short*)(ws + Mrows * K * 2);
    unsigned int* ma = (unsigned int*)(ws + Mrows * K * 2 + (size_t)Nout * K * 2);
    unsigned int* mw = ma + K;

    hipMemsetAsync(ma, 0, 2 * K * sizeof(unsigned int), stream);

    dim3 blk(256);
    {
        int xBlocks = (int)(Mrows / 64);              // 128
        int wBlocks = Nout / 64;                      // 64
        dim3 g(K / 1024, xBlocks + wBlocks);
        maxes_kernel<<<g, blk, 0, stream>>>(x, (int)Mrows, W, Nout, ma, mw, Wb, K, xBlocks);
    }
    {
        size_t ngroups = Mrows * K / 4;
        prune_kernel<<<dim3(2048), blk, 0, stream>>>(x, ma, mw, Xsp, ngroups, K);
    }
    {
        dim3 g((unsigned)((Mrows / 256) * (Nout / 256)));
        gemm_bt256<<<g, dim3(512), 0, stream>>>(Xsp, Wb, out, (int)Mrows, Nout, K);
    }
}